// Round 10
// baseline (121.036 us; speedup 1.0000x reference)
//
#include <hip/hip_runtime.h>
#include <cmath>

// PositionIntervalLoss: B=65536 rows, F=300. One wave per row, 4 rows/block.
// Lane l (<60) owns elements [5l,5l+5). fp64 blur + fp64 prefix sums REQUIRED
// (fp32 prefix error ~1e-4 flips (sm <> +-1) comparisons — round-3 failure).
// Round-9: fp64 wave scan via DPP row_shr/row_bcast (pure VALU).
// Round-10: ALL distance-1 shuffles (halo + peak neighbors) via DPP
// wave_shr:1 / wave_shl:1 — no ds_permute left in the kernel.

constexpr int FLEN = 300;
constexpr int RPB  = 4;
constexpr int SMAX = 152;

// DPP-move with identity 0 for unselected/invalid lanes.
template <int CTRL, int RMASK>
__device__ __forceinline__ double dpp0_f64(double x) {
    union { double d; int i[2]; } u, r;
    u.d = x;
    r.i[0] = __builtin_amdgcn_update_dpp(0, u.i[0], CTRL, RMASK, 0xf, false);
    r.i[1] = __builtin_amdgcn_update_dpp(0, u.i[1], CTRL, RMASK, 0xf, false);
    return r.d;
}
template <int CTRL, int RMASK>
__device__ __forceinline__ float dpp0_f32(float x) {
    union { float f; int i; } u, r;
    u.f = x;
    r.i = __builtin_amdgcn_update_dpp(0, u.i, CTRL, RMASK, 0xf, false);
    return r.f;
}
// wave-wide lane shifts (GCN DPP, kept on CDNA): lane l <- lane l-1 / l+1,
// edge lane gets 0 (old=0, bound_ctrl off).
__device__ __forceinline__ float wshr1(float x) { return dpp0_f32<0x138, 0xf>(x); }
__device__ __forceinline__ float wshl1(float x) { return dpp0_f32<0x130, 0xf>(x); }

__global__ __launch_bounds__(256, 8)
void pil_kernel(const float* __restrict__ in, float* __restrict__ out,
                double bk0, double bk1, double bk2, double bk3)
{
    const int w    = threadIdx.x >> 6;
    const int lane = threadIdx.x & 63;
    const int row  = blockIdx.x * RPB + w;

    __shared__ double2        eg_s[RPB][FLEN];   // eg[t]=(sum_{u<t} e_u, sum_{u<t} e_u*fr_u)
    __shared__ unsigned short ps_s[RPB][SMAX];   // sorted peak positions

    double2*        eg = eg_s[w];
    unsigned short* ps = ps_s[w];

    const float* rin  = in + (size_t)row * FLEN;
    const int    base = lane * 5;
    const bool   act  = (lane < 60);
    const int    bC   = act ? base : 295;          // clamp OOB lanes (unused)

    // ---- load own 5 raw values; halo via DPP wave shifts ----
    float r0 = rin[bC+0], r1 = rin[bC+1], r2 = rin[bC+2], r3 = rin[bC+3], r4 = rin[bC+4];
    float l2 = wshr1(r2), l3 = wshr1(r3), l4 = wshr1(r4);   // lane 0 -> 0 (zero pad)
    float h0 = wshl1(r0), h1 = wshl1(r1), h2 = wshl1(r2);
    if (lane >= 59) { h0 = 0.f; h1 = 0.f; h2 = 0.f; }       // zero pad right of 299

    // ---- 7-tap symmetric blur, fp64 FMA accumulate (fp32-rounded coeffs) ----
    const double d0=(double)l2, d1=(double)l3, d2=(double)l4, d3=(double)r0,
                 d4=(double)r1, d5=(double)r2, d6=(double)r3, d7=(double)r4,
                 d8=(double)h0, d9=(double)h1, d10=(double)h2;
    float f[5];
    f[0] = (float)fma(bk0, d0+d6,  fma(bk1, d1+d5, fma(bk2, d2+d4, bk3*d3)));
    f[1] = (float)fma(bk0, d1+d7,  fma(bk1, d2+d6, fma(bk2, d3+d5, bk3*d4)));
    f[2] = (float)fma(bk0, d2+d8,  fma(bk1, d3+d7, fma(bk2, d4+d6, bk3*d5)));
    f[3] = (float)fma(bk0, d3+d9,  fma(bk1, d4+d8, fma(bk2, d5+d7, bk3*d6)));
    f[4] = (float)fma(bk0, d4+d10, fma(bk1, d5+d9, fma(bk2, d6+d8, bk3*d7)));

    // ---- strict peaks (boundary = -inf sentinel), neighbors via DPP ----
    float fm1 = wshr1(f[4]);
    float fp1 = wshl1(f[0]);
    if (lane == 0)  fm1 = -__builtin_inff();
    if (lane >= 59) fp1 = -__builtin_inff();

    bool p[5];
    {
        float lft = fm1;
        #pragma unroll
        for (int j = 0; j < 5; ++j) {
            float rgt = (j < 4) ? f[j+1] : fp1;
            p[j] = act && (f[j] > lft) && (f[j] > rgt);
            lft = f[j];
        }
    }

    // ---- compaction: ballot + mbcnt (popcount of mask & lanemask_lt) ----
    unsigned long long b0 = __ballot(p[0]), b1 = __ballot(p[1]), b2 = __ballot(p[2]),
                       b3 = __ballot(p[3]), b4 = __ballot(p[4]);
    int off = 0;
    off = __builtin_amdgcn_mbcnt_lo((unsigned)b0, off);
    off = __builtin_amdgcn_mbcnt_hi((unsigned)(b0 >> 32), off);
    off = __builtin_amdgcn_mbcnt_lo((unsigned)b1, off);
    off = __builtin_amdgcn_mbcnt_hi((unsigned)(b1 >> 32), off);
    off = __builtin_amdgcn_mbcnt_lo((unsigned)b2, off);
    off = __builtin_amdgcn_mbcnt_hi((unsigned)(b2 >> 32), off);
    off = __builtin_amdgcn_mbcnt_lo((unsigned)b3, off);
    off = __builtin_amdgcn_mbcnt_hi((unsigned)(b3 >> 32), off);
    off = __builtin_amdgcn_mbcnt_lo((unsigned)b4, off);
    off = __builtin_amdgcn_mbcnt_hi((unsigned)(b4 >> 32), off);
    const int P = __popcll(b0) + __popcll(b1) + __popcll(b2) + __popcll(b3) + __popcll(b4);
    #pragma unroll
    for (int j = 0; j < 5; ++j)
        if (p[j]) ps[off++] = (unsigned short)(base + j);

    // ---- per-element exp / freq; intra-lane inclusive prefixes in fp64 ----
    double cE[5], cG[5];
    double tE = 0.0, tG = 0.0;
    #pragma unroll
    for (int j = 0; j < 5; ++j) {
        int  i = base + j;
        bool v = act && (i < FLEN - 1);
        float e  = v ? __expf(f[j]) : 0.f;    // |f|<~3: unstable softmax identical
        float fr = fmaf((float)(i - 99), 0.02f, -1.0f);   // ((i+1)-100)/100*2-1
        double de = (double)e;
        tE += de;
        tG  = fma(de, (double)fr, tG);
        cE[j] = tE; cG[j] = tG;
    }

    // ---- wave64 inclusive scan of lane totals: DPP (pure VALU) ----
    double sE = tE, sG = tG;
    sE += dpp0_f64<0x111, 0xf>(sE);  sG += dpp0_f64<0x111, 0xf>(sG);  // row_shr:1
    sE += dpp0_f64<0x112, 0xf>(sE);  sG += dpp0_f64<0x112, 0xf>(sG);  // row_shr:2
    sE += dpp0_f64<0x114, 0xf>(sE);  sG += dpp0_f64<0x114, 0xf>(sG);  // row_shr:4
    sE += dpp0_f64<0x118, 0xf>(sE);  sG += dpp0_f64<0x118, 0xf>(sG);  // row_shr:8
    sE += dpp0_f64<0x142, 0xa>(sE);  sG += dpp0_f64<0x142, 0xa>(sG);  // row_bcast:15 -> rows 1,3
    sE += dpp0_f64<0x143, 0xc>(sE);  sG += dpp0_f64<0x143, 0xc>(sG);  // row_bcast:31 -> rows 2,3
    const double xE = sE - tE, xG = sG - tG;   // exclusive prefix of lane totals

    if (lane == 63) eg[0] = make_double2(0.0, 0.0);
    #pragma unroll
    for (int j = 0; j < 5; ++j) {
        int i = base + j;
        if (act && i <= FLEN - 2)
            eg[i + 1] = make_double2(xE + cE[j], xG + cG[j]);
    }

    // ---- wave-local LDS fence (this wave is sole owner of its row slice;
    //      same-wave DS ops execute in order — no s_barrier needed) ----
    __builtin_amdgcn_wave_barrier();
    __asm__ volatile("s_waitcnt lgkmcnt(0)" ::: "memory");
    __builtin_amdgcn_wave_barrier();

    // ---- per-segment softargmax = prefix difference; O(1) per segment ----
    const int nseg = (P > 0) ? P : 1;
    float sum_in = 0.f; int any_in = 0;
    for (int s = lane; s < nseg; s += 64) {
        int im = (s > 0) ? s - 1 : 0;
        int ip = (s < P - 1) ? s + 1 : im;
        int pm = ps[im], pc = ps[(P > 0) ? s : 0], pn = ps[ip];
        int lo = (s == 0)        ? 0        : ((pm + pc) >> 1);
        int hi = (s == nseg - 1) ? FLEN - 1 : ((pc + pn) >> 1);
        double2 a = eg[lo], b = eg[hi];
        float den = (float)(b.x - a.x);         // exact to ~1e-13, > 0
        float num = (float)(b.y - a.y);
        float sm  = num / den;
        bool  ii  = (sm > -1.0f) && (sm < 1.0f);
        if (ii) { sum_in -= sm * sm; any_in = 1; }
    }

    // ---- common path: some segment in-interval (one ballot decides) ----
    if (__ballot(any_in) != 0ull) {
        // DPP scan-reduce: lane 63 ends with the wave total
        sum_in += dpp0_f32<0x111, 0xf>(sum_in);
        sum_in += dpp0_f32<0x112, 0xf>(sum_in);
        sum_in += dpp0_f32<0x114, 0xf>(sum_in);
        sum_in += dpp0_f32<0x118, 0xf>(sum_in);
        sum_in += dpp0_f32<0x142, 0xa>(sum_in);
        sum_in += dpp0_f32<0x143, 0xc>(sum_in);
        if (lane == 63) out[row] = sum_in;
    } else {
        // rare fallback (wave-uniform): recompute, track two largest nsq
        float m1 = -__builtin_inff(), m2 = -__builtin_inff();
        for (int s = lane; s < nseg; s += 64) {
            int im = (s > 0) ? s - 1 : 0;
            int ip = (s < P - 1) ? s + 1 : im;
            int pm = ps[im], pc = ps[(P > 0) ? s : 0], pn = ps[ip];
            int lo = (s == 0)        ? 0        : ((pm + pc) >> 1);
            int hi = (s == nseg - 1) ? FLEN - 1 : ((pc + pn) >> 1);
            double2 a = eg[lo], b = eg[hi];
            float den = (float)(b.x - a.x);
            float num = (float)(b.y - a.y);
            float sm  = num / den;
            float nsq = -(sm * sm);
            if (nsq > m1) { m2 = m1; m1 = nsq; } else { m2 = fmaxf(m2, nsq); }
        }
        #pragma unroll
        for (int d = 32; d >= 1; d >>= 1) {
            float o1 = __shfl_xor(m1, d);
            float o2 = __shfl_xor(m2, d);
            float n1 = fmaxf(m1, o1);
            float n2 = fmaxf(fminf(m1, o1), fmaxf(m2, o2));
            m1 = n1; m2 = n2;
        }
        if (lane == 0) {
            float t2 = m1 + ((m2 > -__builtin_inff()) ? m2 : 0.0f);
            out[row] = t2;
        }
    }
}

extern "C" void kernel_launch(void* const* d_in, const int* in_sizes, int n_in,
                              void* d_out, int out_size, void* d_ws, size_t ws_size,
                              hipStream_t stream) {
    const float* in  = (const float*)d_in[0];
    float*       out = (float*)d_out;
    const int B = in_sizes[0] / FLEN;          // 65536

    // Gaussian kernel sigma=2, l=7: double, normalized, rounded to fp32
    // (matching jnp.asarray(k/k.sum(), float32)), widened back to double.
    double k[7], s = 0.0;
    for (int t = 0; t < 7; ++t) {
        double x = -3.0 + (double)t;
        k[t] = exp(-0.5 * x * x / 4.0);
        s += k[t];
    }
    double bk0 = (double)(float)(k[0] / s);
    double bk1 = (double)(float)(k[1] / s);
    double bk2 = (double)(float)(k[2] / s);
    double bk3 = (double)(float)(k[3] / s);

    pil_kernel<<<B / RPB, 256, 0, stream>>>(in, out, bk0, bk1, bk2, bk3);
}

// Round 11
// 120.586 us; speedup vs baseline: 1.0037x; 1.0037x over previous
//
#include <hip/hip_runtime.h>
#include <cmath>

// PositionIntervalLoss: B=65536 rows, F=300. One wave per row, 4 rows/block.
// Lane l (<60) owns elements [5l,5l+5). fp64 blur + fp64 prefix sums REQUIRED
// (fp32 prefix error ~1e-4 flips (sm <> +-1) comparisons — round-3 failure).
// R9: fp64 wave scan via DPP row_shr/row_bcast (pure VALU). R10: distance-1
// shuffles via DPP wave_shr/wave_shl. R11: guard simplification (two static
// lane masks instead of per-element bounds compares) + shared-base eg scatter
// (one vaddr + constant ds_write offsets).

constexpr int FLEN = 300;
constexpr int RPB  = 4;
constexpr int SMAX = 152;

// DPP-move with identity 0 for unselected/invalid lanes.
template <int CTRL, int RMASK>
__device__ __forceinline__ double dpp0_f64(double x) {
    union { double d; int i[2]; } u, r;
    u.d = x;
    r.i[0] = __builtin_amdgcn_update_dpp(0, u.i[0], CTRL, RMASK, 0xf, false);
    r.i[1] = __builtin_amdgcn_update_dpp(0, u.i[1], CTRL, RMASK, 0xf, false);
    return r.d;
}
template <int CTRL, int RMASK>
__device__ __forceinline__ float dpp0_f32(float x) {
    union { float f; int i; } u, r;
    u.f = x;
    r.i = __builtin_amdgcn_update_dpp(0, u.i, CTRL, RMASK, 0xf, false);
    return r.f;
}
// wave-wide lane shifts: lane l <- lane l-1 / l+1, edge lane gets 0.
__device__ __forceinline__ float wshr1(float x) { return dpp0_f32<0x138, 0xf>(x); }
__device__ __forceinline__ float wshl1(float x) { return dpp0_f32<0x130, 0xf>(x); }

__global__ __launch_bounds__(256, 8)
void pil_kernel(const float* __restrict__ in, float* __restrict__ out,
                double bk0, double bk1, double bk2, double bk3)
{
    const int w    = threadIdx.x >> 6;
    const int lane = threadIdx.x & 63;
    const int row  = blockIdx.x * RPB + w;

    __shared__ double2        eg_s[RPB][FLEN];   // eg[t]=(sum_{u<t} e_u, sum_{u<t} e_u*fr_u)
    __shared__ unsigned short ps_s[RPB][SMAX];   // sorted peak positions

    double2*        eg = eg_s[w];
    unsigned short* ps = ps_s[w];

    const float* rin  = in + (size_t)row * FLEN;
    const int    base = lane * 5;
    const bool   act   = (lane < 60);   // owns any element
    const bool   act59 = (lane < 59);   // j=4 element is < 299
    const int    bC   = act ? base : 295;          // clamp OOB lanes (unused)

    // ---- load own 5 raw values; halo via DPP wave shifts ----
    float r0 = rin[bC+0], r1 = rin[bC+1], r2 = rin[bC+2], r3 = rin[bC+3], r4 = rin[bC+4];
    float l2 = wshr1(r2), l3 = wshr1(r3), l4 = wshr1(r4);   // lane 0 -> 0 (zero pad)
    float h0 = wshl1(r0), h1 = wshl1(r1), h2 = wshl1(r2);
    if (lane >= 59) { h0 = 0.f; h1 = 0.f; h2 = 0.f; }       // zero pad right of 299

    // ---- 7-tap symmetric blur, fp64 FMA accumulate (fp32-rounded coeffs) ----
    const double d0=(double)l2, d1=(double)l3, d2=(double)l4, d3=(double)r0,
                 d4=(double)r1, d5=(double)r2, d6=(double)r3, d7=(double)r4,
                 d8=(double)h0, d9=(double)h1, d10=(double)h2;
    float f[5];
    f[0] = (float)fma(bk0, d0+d6,  fma(bk1, d1+d5, fma(bk2, d2+d4, bk3*d3)));
    f[1] = (float)fma(bk0, d1+d7,  fma(bk1, d2+d6, fma(bk2, d3+d5, bk3*d4)));
    f[2] = (float)fma(bk0, d2+d8,  fma(bk1, d3+d7, fma(bk2, d4+d6, bk3*d5)));
    f[3] = (float)fma(bk0, d3+d9,  fma(bk1, d4+d8, fma(bk2, d5+d7, bk3*d6)));
    f[4] = (float)fma(bk0, d4+d10, fma(bk1, d5+d9, fma(bk2, d6+d8, bk3*d7)));

    // ---- strict peaks (boundary = -inf sentinel), neighbors via DPP ----
    float fm1 = wshr1(f[4]);
    float fp1 = wshl1(f[0]);
    if (lane == 0)  fm1 = -__builtin_inff();
    if (lane >= 59) fp1 = -__builtin_inff();

    bool p[5];
    {
        float lft = fm1;
        #pragma unroll
        for (int j = 0; j < 5; ++j) {
            float rgt = (j < 4) ? f[j+1] : fp1;
            p[j] = act && (f[j] > lft) && (f[j] > rgt);
            lft = f[j];
        }
    }

    // ---- compaction: ballot + mbcnt (popcount of mask & lanemask_lt) ----
    unsigned long long b0 = __ballot(p[0]), b1 = __ballot(p[1]), b2 = __ballot(p[2]),
                       b3 = __ballot(p[3]), b4 = __ballot(p[4]);
    int off = 0;
    off = __builtin_amdgcn_mbcnt_lo((unsigned)b0, off);
    off = __builtin_amdgcn_mbcnt_hi((unsigned)(b0 >> 32), off);
    off = __builtin_amdgcn_mbcnt_lo((unsigned)b1, off);
    off = __builtin_amdgcn_mbcnt_hi((unsigned)(b1 >> 32), off);
    off = __builtin_amdgcn_mbcnt_lo((unsigned)b2, off);
    off = __builtin_amdgcn_mbcnt_hi((unsigned)(b2 >> 32), off);
    off = __builtin_amdgcn_mbcnt_lo((unsigned)b3, off);
    off = __builtin_amdgcn_mbcnt_hi((unsigned)(b3 >> 32), off);
    off = __builtin_amdgcn_mbcnt_lo((unsigned)b4, off);
    off = __builtin_amdgcn_mbcnt_hi((unsigned)(b4 >> 32), off);
    const int P = __popcll(b0) + __popcll(b1) + __popcll(b2) + __popcll(b3) + __popcll(b4);
    #pragma unroll
    for (int j = 0; j < 5; ++j)
        if (p[j]) ps[off++] = (unsigned short)(base + j);

    // ---- per-element exp / freq; intra-lane inclusive prefixes in fp64.
    //      Validity masks are static per j: j<4 -> act, j==4 -> act59. ----
    double cE[5], cG[5];
    double tE = 0.0, tG = 0.0;
    #pragma unroll
    for (int j = 0; j < 5; ++j) {
        bool v = (j < 4) ? act : act59;
        float e  = v ? __expf(f[j]) : 0.f;    // |f|<~3: unstable softmax identical
        float fr = fmaf((float)(base + j - 99), 0.02f, -1.0f);  // ((i+1)-100)/100*2-1
        double de = (double)e;
        tE += de;
        tG  = fma(de, (double)fr, tG);
        cE[j] = tE; cG[j] = tG;
    }

    // ---- wave64 inclusive scan of lane totals: DPP (pure VALU) ----
    double sE = tE, sG = tG;
    sE += dpp0_f64<0x111, 0xf>(sE);  sG += dpp0_f64<0x111, 0xf>(sG);  // row_shr:1
    sE += dpp0_f64<0x112, 0xf>(sE);  sG += dpp0_f64<0x112, 0xf>(sG);  // row_shr:2
    sE += dpp0_f64<0x114, 0xf>(sE);  sG += dpp0_f64<0x114, 0xf>(sG);  // row_shr:4
    sE += dpp0_f64<0x118, 0xf>(sE);  sG += dpp0_f64<0x118, 0xf>(sG);  // row_shr:8
    sE += dpp0_f64<0x142, 0xa>(sE);  sG += dpp0_f64<0x142, 0xa>(sG);  // row_bcast:15
    sE += dpp0_f64<0x143, 0xc>(sE);  sG += dpp0_f64<0x143, 0xc>(sG);  // row_bcast:31
    const double xE = sE - tE, xG = sG - tG;   // exclusive prefix of lane totals

    // ---- scatter inclusive prefixes: one shared base, const offsets ----
    if (lane == 63) eg[0] = make_double2(0.0, 0.0);
    if (act) {
        double2* egp = &eg[base + 1];
        egp[0] = make_double2(xE + cE[0], xG + cG[0]);
        egp[1] = make_double2(xE + cE[1], xG + cG[1]);
        egp[2] = make_double2(xE + cE[2], xG + cG[2]);
        egp[3] = make_double2(xE + cE[3], xG + cG[3]);
        if (act59)
            egp[4] = make_double2(xE + cE[4], xG + cG[4]);
    }

    // ---- wave-local LDS fence (this wave is sole owner of its row slice;
    //      same-wave DS ops execute in order — no s_barrier needed) ----
    __builtin_amdgcn_wave_barrier();
    __asm__ volatile("s_waitcnt lgkmcnt(0)" ::: "memory");
    __builtin_amdgcn_wave_barrier();

    // ---- per-segment softargmax = prefix difference; O(1) per segment ----
    const int nseg = (P > 0) ? P : 1;
    float sum_in = 0.f; int any_in = 0;
    for (int s = lane; s < nseg; s += 64) {
        int im = (s > 0) ? s - 1 : 0;
        int ip = (s < P - 1) ? s + 1 : im;
        int pm = ps[im], pc = ps[(P > 0) ? s : 0], pn = ps[ip];
        int lo = (s == 0)        ? 0        : ((pm + pc) >> 1);
        int hi = (s == nseg - 1) ? FLEN - 1 : ((pc + pn) >> 1);
        double2 a = eg[lo], b = eg[hi];
        float den = (float)(b.x - a.x);         // exact to ~1e-13, > 0
        float num = (float)(b.y - a.y);
        float sm  = num / den;
        bool  ii  = (sm > -1.0f) && (sm < 1.0f);
        if (ii) { sum_in -= sm * sm; any_in = 1; }
    }

    // ---- common path: some segment in-interval (one ballot decides) ----
    if (__ballot(any_in) != 0ull) {
        // DPP scan-reduce: lane 63 ends with the wave total
        sum_in += dpp0_f32<0x111, 0xf>(sum_in);
        sum_in += dpp0_f32<0x112, 0xf>(sum_in);
        sum_in += dpp0_f32<0x114, 0xf>(sum_in);
        sum_in += dpp0_f32<0x118, 0xf>(sum_in);
        sum_in += dpp0_f32<0x142, 0xa>(sum_in);
        sum_in += dpp0_f32<0x143, 0xc>(sum_in);
        if (lane == 63) out[row] = sum_in;
    } else {
        // rare fallback (wave-uniform): recompute, track two largest nsq
        float m1 = -__builtin_inff(), m2 = -__builtin_inff();
        for (int s = lane; s < nseg; s += 64) {
            int im = (s > 0) ? s - 1 : 0;
            int ip = (s < P - 1) ? s + 1 : im;
            int pm = ps[im], pc = ps[(P > 0) ? s : 0], pn = ps[ip];
            int lo = (s == 0)        ? 0        : ((pm + pc) >> 1);
            int hi = (s == nseg - 1) ? FLEN - 1 : ((pc + pn) >> 1);
            double2 a = eg[lo], b = eg[hi];
            float den = (float)(b.x - a.x);
            float num = (float)(b.y - a.y);
            float sm  = num / den;
            float nsq = -(sm * sm);
            if (nsq > m1) { m2 = m1; m1 = nsq; } else { m2 = fmaxf(m2, nsq); }
        }
        #pragma unroll
        for (int d = 32; d >= 1; d >>= 1) {
            float o1 = __shfl_xor(m1, d);
            float o2 = __shfl_xor(m2, d);
            float n1 = fmaxf(m1, o1);
            float n2 = fmaxf(fminf(m1, o1), fmaxf(m2, o2));
            m1 = n1; m2 = n2;
        }
        if (lane == 0) {
            float t2 = m1 + ((m2 > -__builtin_inff()) ? m2 : 0.0f);
            out[row] = t2;
        }
    }
}

extern "C" void kernel_launch(void* const* d_in, const int* in_sizes, int n_in,
                              void* d_out, int out_size, void* d_ws, size_t ws_size,
                              hipStream_t stream) {
    const float* in  = (const float*)d_in[0];
    float*       out = (float*)d_out;
    const int B = in_sizes[0] / FLEN;          // 65536

    // Gaussian kernel sigma=2, l=7: double, normalized, rounded to fp32
    // (matching jnp.asarray(k/k.sum(), float32)), widened back to double.
    double k[7], s = 0.0;
    for (int t = 0; t < 7; ++t) {
        double x = -3.0 + (double)t;
        k[t] = exp(-0.5 * x * x / 4.0);
        s += k[t];
    }
    double bk0 = (double)(float)(k[0] / s);
    double bk1 = (double)(float)(k[1] / s);
    double bk2 = (double)(float)(k[2] / s);
    double bk3 = (double)(float)(k[3] / s);

    pil_kernel<<<B / RPB, 256, 0, stream>>>(in, out, bk0, bk1, bk2, bk3);
}